// Round 5
// baseline (180.568 us; speedup 1.0000x reference)
//
#include <hip/hip_runtime.h>

#define N_NODES 100000
#define N_EDGES 1250000
#define IN_CH 64
#define HID 128
#define OUT_CH 2
#define NUM_GRAPHS 128
#define NREP 4  // replicated list heads: less atomic contention + 4-way walk ILP

typedef _Float16 half2v __attribute__((ext_vector_type(2)));
typedef _Float16 half8 __attribute__((ext_vector_type(8)));
typedef float f32x4 __attribute__((ext_vector_type(4)));

#define EDGE_BLOCKS ((N_EDGES + 255) / 256)            // 4883
#define XCAST_BLOCKS (N_NODES * IN_CH / 4 / 256)       // 6250
#define WPREP_BLOCKS ((HID * 2 * IN_CH + 255) / 256)   // 64

// ---------------------------------------------------------------------------
// K1: fused prep. Block ranges: [0,EDGE) list-build, [EDGE,EDGE+XCAST) x->f16,
// then weight prep. List-build: the ONLY scattered op is atomicExch on the
// 1.6MB head array; pair[e]={src,prev} is a coalesced 8B store (vs R4's
// random 4B store into 16MB wsrc -> 74.5MB partial-line write traffic).
// ---------------------------------------------------------------------------
__global__ __launch_bounds__(256) void prep_k(const float* __restrict__ x,
                                              const float* __restrict__ W_l,
                                              const float* __restrict__ W_r,
                                              const int* __restrict__ ei,
                                              unsigned short* __restrict__ xh,
                                              unsigned short* __restrict__ Wc,
                                              int* __restrict__ head,
                                              int2* __restrict__ pair) {
    const int b = (int)blockIdx.x;
    const int tid = (int)threadIdx.x;
    if (b < EDGE_BLOCKS) {
        const int e = b * 256 + tid;
        if (e < N_EDGES) {
            const int src = ei[e];
            const int dst = ei[N_EDGES + e];
            const int old = atomicExch(&head[(e & (NREP - 1)) * N_NODES + dst], e);
            pair[e] = make_int2(src, old);
        }
        return;
    }
    const int b2 = b - EDGE_BLOCKS;
    if (b2 < XCAST_BLOCKS) {
        const int i = b2 * 256 + tid;  // < 1.6M float4 units
        const float4 v = reinterpret_cast<const float4*>(x)[i];
        half2v a, c;
        a[0] = (_Float16)v.x; a[1] = (_Float16)v.y;
        c[0] = (_Float16)v.z; c[1] = (_Float16)v.w;
        uint2 u;
        u.x = __builtin_bit_cast(unsigned, a);
        u.y = __builtin_bit_cast(unsigned, c);
        reinterpret_cast<uint2*>(xh)[i] = u;
        return;
    }
    const int i = (b2 - XCAST_BLOCKS) * 256 + tid;  // < 16384
    if (i < HID * 2 * IN_CH) {
        const int o = i >> 7;
        const int k = i & 127;
        const float v = (k < IN_CH) ? W_l[o * IN_CH + k] : W_r[o * IN_CH + (k - IN_CH)];
        const _Float16 h = (_Float16)v;
        Wc[i] = __builtin_bit_cast(unsigned short, h);
    }
}

// ---------------------------------------------------------------------------
// K2: mean by list walk. One thread per node; 4 chains interleaved (4
// pointer-chase loads in flight). Row accumulate in 64 f32 regs. deg = hop
// count (exact -- no CAP truncation). All 391 blocks co-resident.
// ---------------------------------------------------------------------------
__device__ __forceinline__ void accrow(const unsigned short* __restrict__ xh,
                                       int s, float4* acc) {
    const uint4* row = reinterpret_cast<const uint4*>(xh + (size_t)s * IN_CH);
#pragma unroll
    for (int j = 0; j < 8; ++j) {
        const uint4 v = row[j];
        const half2v h0 = __builtin_bit_cast(half2v, v.x);
        const half2v h1 = __builtin_bit_cast(half2v, v.y);
        const half2v h2 = __builtin_bit_cast(half2v, v.z);
        const half2v h3 = __builtin_bit_cast(half2v, v.w);
        acc[2 * j].x += (float)h0[0];
        acc[2 * j].y += (float)h0[1];
        acc[2 * j].z += (float)h1[0];
        acc[2 * j].w += (float)h1[1];
        acc[2 * j + 1].x += (float)h2[0];
        acc[2 * j + 1].y += (float)h2[1];
        acc[2 * j + 1].z += (float)h3[0];
        acc[2 * j + 1].w += (float)h3[1];
    }
}

__global__ __launch_bounds__(256) void meanwalk_k(const unsigned short* __restrict__ xh,
                                                  const int* __restrict__ head,
                                                  const int2* __restrict__ pair,
                                                  unsigned short* __restrict__ meanh) {
    const int n = (int)(blockIdx.x * 256 + threadIdx.x);
    if (n >= N_NODES) return;

    float4 acc[16];
#pragma unroll
    for (int i = 0; i < 16; ++i) acc[i] = make_float4(0.f, 0.f, 0.f, 0.f);

    int c0 = head[n];
    int c1 = head[N_NODES + n];
    int c2 = head[2 * N_NODES + n];
    int c3 = head[3 * N_NODES + n];
    int deg = 0;

    while (max(max(c0, c1), max(c2, c3)) >= 0) {
        const bool a0 = c0 >= 0, a1 = c1 >= 0, a2 = c2 >= 0, a3 = c3 >= 0;
        int2 p0, p1, p2, p3;
        if (a0) p0 = pair[c0];
        if (a1) p1 = pair[c1];
        if (a2) p2 = pair[c2];
        if (a3) p3 = pair[c3];
        if (a0) { accrow(xh, p0.x, acc); c0 = p0.y; ++deg; }
        if (a1) { accrow(xh, p1.x, acc); c1 = p1.y; ++deg; }
        if (a2) { accrow(xh, p2.x, acc); c2 = p2.y; ++deg; }
        if (a3) { accrow(xh, p3.x, acc); c3 = p3.y; ++deg; }
    }

    const float rcp = 1.0f / fmaxf((float)deg, 1.0f);
    uint4 outv[4];
#pragma unroll
    for (int j = 0; j < 8; ++j) {
        half2v lo, hi;
        lo[0] = (_Float16)(acc[2 * j].x * rcp);
        lo[1] = (_Float16)(acc[2 * j].y * rcp);
        hi[0] = (_Float16)(acc[2 * j].z * rcp);
        hi[1] = (_Float16)(acc[2 * j].w * rcp);
        half2v lo2, hi2;
        lo2[0] = (_Float16)(acc[2 * j + 1].x * rcp);
        lo2[1] = (_Float16)(acc[2 * j + 1].y * rcp);
        hi2[0] = (_Float16)(acc[2 * j + 1].z * rcp);
        hi2[1] = (_Float16)(acc[2 * j + 1].w * rcp);
        uint4& o4 = outv[j >> 1];
        if ((j & 1) == 0) {
            o4.x = __builtin_bit_cast(unsigned, lo);
            o4.y = __builtin_bit_cast(unsigned, hi);
        } else {
            o4.z = __builtin_bit_cast(unsigned, lo2);
            o4.w = __builtin_bit_cast(unsigned, hi2);
        }
    }
    // note: outv packing above mixes acc pairs; rewrite linearly for clarity
    float vals[16 * 4];
#pragma unroll
    for (int i = 0; i < 16; ++i) {
        vals[4 * i + 0] = acc[i].x * rcp;
        vals[4 * i + 1] = acc[i].y * rcp;
        vals[4 * i + 2] = acc[i].z * rcp;
        vals[4 * i + 3] = acc[i].w * rcp;
    }
    uint4* op = reinterpret_cast<uint4*>(meanh + (size_t)n * IN_CH);
#pragma unroll
    for (int j = 0; j < 8; ++j) {
        half2v lo, hi;
        lo[0] = (_Float16)vals[8 * j + 0];
        lo[1] = (_Float16)vals[8 * j + 1];
        hi[0] = (_Float16)vals[8 * j + 2];
        hi[1] = (_Float16)vals[8 * j + 3];
        half2v lo2, hi2;
        lo2[0] = (_Float16)vals[8 * j + 4];
        lo2[1] = (_Float16)vals[8 * j + 5];
        hi2[0] = (_Float16)vals[8 * j + 6];
        hi2[1] = (_Float16)vals[8 * j + 7];
        uint2 u0, u1;
        u0.x = __builtin_bit_cast(unsigned, lo);
        u0.y = __builtin_bit_cast(unsigned, hi);
        u1.x = __builtin_bit_cast(unsigned, lo2);
        u1.y = __builtin_bit_cast(unsigned, hi2);
        if (j & 1) {
            uint4 prev = op[0];  // placeholder; overwritten below
        }
        reinterpret_cast<uint2*>(op)[2 * j + 0] = u0;
        reinterpret_cast<uint2*>(op)[2 * j + 1] = u1;
    }
}

// ---------------------------------------------------------------------------
// K3: MFMA GEMM (128-node x 128-out, K=128) + relu + per-graph max pool.
// (unchanged from R4 -- verified)
// ---------------------------------------------------------------------------
#define MBLK 128

__device__ __forceinline__ void flushmax(unsigned* lmax, unsigned int* gmax,
                                         int g, int gbase, int l15,
                                         const float* rmax) {
    const int slot = g - gbase;
    if (slot < 4) {
#pragma unroll
        for (int nt = 0; nt < 8; ++nt)
            atomicMax(&lmax[slot * HID + nt * 16 + l15], __float_as_uint(rmax[nt]));
    } else {
#pragma unroll
        for (int nt = 0; nt < 8; ++nt)
            atomicMax(&gmax[(size_t)g * HID + nt * 16 + l15], __float_as_uint(rmax[nt]));
    }
}

__global__ __launch_bounds__(512) void gemm_pool_k(const unsigned short* __restrict__ xh,
                                                   const unsigned short* __restrict__ meanh,
                                                   const unsigned short* __restrict__ Wc,
                                                   const float* __restrict__ b_l,
                                                   const int* __restrict__ batch,
                                                   unsigned int* __restrict__ gmax) {
    __shared__ uint4 fe[MBLK * 16];
    __shared__ uint4 wt[HID * 16];
    __shared__ unsigned lmax[4 * HID];
    __shared__ int bt[MBLK];

    const int tid = (int)threadIdx.x;
    const int nb = (int)blockIdx.x * MBLK;
    const int nvalid = min(MBLK, N_NODES - nb);

#pragma unroll
    for (int t = 0; t < 4; ++t) {
        const int id = tid + t * 512;
        const int row = id >> 4, c = id & 15;
        wt[row * 16 + (c ^ (row & 7))] = reinterpret_cast<const uint4*>(Wc)[row * 16 + c];
    }
#pragma unroll
    for (int t = 0; t < 4; ++t) {
        const int id = tid + t * 512;
        const int row = id >> 4, c = id & 15;
        const int n = nb + row;
        uint4 v = make_uint4(0u, 0u, 0u, 0u);
        if (n < N_NODES) {
            v = (c < 8) ? reinterpret_cast<const uint4*>(meanh)[(size_t)n * 8 + c]
                        : reinterpret_cast<const uint4*>(xh)[(size_t)n * 8 + (c - 8)];
        }
        fe[row * 16 + (c ^ (row & 7))] = v;
    }
    if (tid < MBLK) bt[tid] = (nb + tid < N_NODES) ? batch[nb + tid] : -1;
    for (int i = tid; i < 4 * HID; i += 512) lmax[i] = 0u;
    __syncthreads();

    const int lane = tid & 63;
    const int w = tid >> 6;
    const int l15 = lane & 15, q = lane >> 4;

    f32x4 acc[8];
#pragma unroll
    for (int nt = 0; nt < 8; ++nt) acc[nt] = (f32x4){0.f, 0.f, 0.f, 0.f};

    const int arow = w * 16 + l15;
#pragma unroll
    for (int kb = 0; kb < 4; ++kb) {
        const int ac = kb * 4 + q;
        const half8 a = __builtin_bit_cast(half8, fe[arow * 16 + (ac ^ (arow & 7))]);
#pragma unroll
        for (int nt = 0; nt < 8; ++nt) {
            const int nrow = nt * 16 + l15;
            const half8 b = __builtin_bit_cast(half8, wt[nrow * 16 + (ac ^ (nrow & 7))]);
            acc[nt] = __builtin_amdgcn_mfma_f32_16x16x32_f16(a, b, acc[nt], 0, 0, 0);
        }
    }

    float bias[8];
#pragma unroll
    for (int nt = 0; nt < 8; ++nt) bias[nt] = b_l[nt * 16 + l15];

    const int gbase = bt[0];
    const int rowb = w * 16 + q * 4;
    int curg = -1;
    float rmax[8];
#pragma unroll
    for (int nt = 0; nt < 8; ++nt) rmax[nt] = 0.f;

#pragma unroll
    for (int reg = 0; reg < 4; ++reg) {
        const int g = bt[rowb + reg];
        if (g >= 0) {
            float h[8];
#pragma unroll
            for (int nt = 0; nt < 8; ++nt) h[nt] = fmaxf(acc[nt][reg] + bias[nt], 0.f);
            if (g != curg) {
                if (curg >= 0) flushmax(lmax, gmax, curg, gbase, l15, rmax);
                curg = g;
#pragma unroll
                for (int nt = 0; nt < 8; ++nt) rmax[nt] = h[nt];
            } else {
#pragma unroll
                for (int nt = 0; nt < 8; ++nt) rmax[nt] = fmaxf(rmax[nt], h[nt]);
            }
        }
    }
    if (curg >= 0) flushmax(lmax, gmax, curg, gbase, l15, rmax);
    __syncthreads();

    int span = bt[nvalid - 1] - gbase + 1;
    if (span > 4) span = 4;
    for (int i = tid; i < span * HID; i += 512) {
        const unsigned v = lmax[i];
        if (v) atomicMax(&gmax[(size_t)(gbase + (i >> 7)) * HID + (i & 127)], v);
    }
}

// ---------------------------------------------------------------------------
// K4: head. out[g][oc] = gmax[g].W_lin[oc] + b_lin[oc]
// ---------------------------------------------------------------------------
__global__ __launch_bounds__(256) void head_k(const unsigned int* __restrict__ gmax_u,
                                              const float* __restrict__ W_lin,
                                              const float* __restrict__ b_lin,
                                              float* __restrict__ out) {
    const int t = (int)threadIdx.x;
    const int g = t >> 1;
    const int oc = t & 1;
    const float* gm = (const float*)gmax_u;
    float acc = b_lin[oc];
#pragma unroll 4
    for (int k = 0; k < HID; ++k) acc += gm[(size_t)g * HID + k] * W_lin[oc * HID + k];
    out[(size_t)g * OUT_CH + oc] = acc;
}

extern "C" void kernel_launch(void* const* d_in, const int* in_sizes, int n_in,
                              void* d_out, int out_size, void* d_ws, size_t ws_size,
                              hipStream_t stream) {
    const float* x = (const float*)d_in[0];
    const float* W_l = (const float*)d_in[1];
    const float* b_l = (const float*)d_in[2];
    const float* W_r = (const float*)d_in[3];
    const float* W_lin = (const float*)d_in[4];
    const float* b_lin = (const float*)d_in[5];
    const int* ei = (const int*)d_in[6];
    const int* batch = (const int*)d_in[7];
    float* out = (float*)d_out;

    char* ws = (char*)d_ws;
    size_t off = 0;
    int* head = (int*)(ws + off); off += (size_t)NREP * N_NODES * 4;                       // 1.6MB
    int2* pair = (int2*)(ws + off); off += (size_t)N_EDGES * 8;                            // 10MB
    unsigned short* xh = (unsigned short*)(ws + off); off += (size_t)N_NODES * IN_CH * 2;  // 12.8MB
    unsigned short* meanh = (unsigned short*)(ws + off); off += (size_t)N_NODES * IN_CH * 2;
    unsigned short* Wc = (unsigned short*)(ws + off); off += (size_t)HID * 2 * IN_CH * 2;
    unsigned int* gmax = (unsigned int*)(ws + off); off += (size_t)NUM_GRAPHS * HID * 4;

    hipMemsetAsync(head, 0xFF, (size_t)NREP * N_NODES * 4, stream);  // all -1
    hipMemsetAsync(gmax, 0, (size_t)NUM_GRAPHS * HID * 4, stream);

    prep_k<<<EDGE_BLOCKS + XCAST_BLOCKS + WPREP_BLOCKS, 256, 0, stream>>>(
        x, W_l, W_r, ei, xh, Wc, head, pair);
    meanwalk_k<<<(N_NODES + 255) / 256, 256, 0, stream>>>(xh, head, pair, meanh);
    gemm_pool_k<<<(N_NODES + MBLK - 1) / MBLK, 512, 0, stream>>>(xh, meanh, Wc, b_l, batch, gmax);
    head_k<<<1, 256, 0, stream>>>(gmax, W_lin, b_lin, out);
}

// Round 6
// 105.192 us; speedup vs baseline: 1.7166x; 1.7166x over previous
//
#include <hip/hip_runtime.h>

#define N_NODES 100000
#define N_EDGES 1250000
#define IN_CH 64
#define HID 128
#define OUT_CH 2
#define NUM_GRAPHS 128

#define PSHIFT 8
#define PSIZE 256                      // nodes per partition
#define NPART ((N_NODES + PSIZE - 1) / PSIZE)  // 391
#define MAXE 4096                      // max edges/partition (mean 3197, sigma 56 -> 16-sigma safe)
#define TILE 4096                      // edges per part_k block

typedef _Float16 half2v __attribute__((ext_vector_type(2)));
typedef _Float16 half8 __attribute__((ext_vector_type(8)));
typedef float f32x4 __attribute__((ext_vector_type(4)));

#define HB 64                                   // histogram blocks
#define XCAST_BLOCKS (N_NODES * IN_CH / 4 / 256)  // 6250
#define WPREP_BLOCKS 64

// ---------------------------------------------------------------------------
// K1 prep: [0,HB) dst-histogram (LDS-privatized), then x->f16 cast, then
// weight prep. No per-edge global atomics: 392x64 flush adds only.
// ---------------------------------------------------------------------------
__global__ __launch_bounds__(256) void prep_k(const float* __restrict__ x,
                                              const float* __restrict__ W_l,
                                              const float* __restrict__ W_r,
                                              const int* __restrict__ ei,
                                              unsigned short* __restrict__ xh,
                                              unsigned short* __restrict__ Wc,
                                              int* __restrict__ ghist) {
    const int b = (int)blockIdx.x;
    const int tid = (int)threadIdx.x;
    if (b < HB) {
        __shared__ int lh[NPART + 1];
        for (int i = tid; i <= NPART; i += 256) lh[i] = 0;
        __syncthreads();
        for (int e = b * 256 + tid; e < N_EDGES; e += HB * 256)
            atomicAdd(&lh[ei[N_EDGES + e] >> PSHIFT], 1);
        __syncthreads();
        for (int i = tid; i < NPART; i += 256)
            if (lh[i]) atomicAdd(&ghist[i], lh[i]);
        return;
    }
    const int b2 = b - HB;
    if (b2 < XCAST_BLOCKS) {
        const int i = b2 * 256 + tid;
        const float4 v = reinterpret_cast<const float4*>(x)[i];
        half2v a, c;
        a[0] = (_Float16)v.x; a[1] = (_Float16)v.y;
        c[0] = (_Float16)v.z; c[1] = (_Float16)v.w;
        uint2 u;
        u.x = __builtin_bit_cast(unsigned, a);
        u.y = __builtin_bit_cast(unsigned, c);
        reinterpret_cast<uint2*>(xh)[i] = u;
        return;
    }
    const int i = (b2 - XCAST_BLOCKS) * 256 + tid;
    if (i < HID * 2 * IN_CH) {
        const int o = i >> 7;
        const int k = i & 127;
        const float v = (k < IN_CH) ? W_l[o * IN_CH + k] : W_r[o * IN_CH + (k - IN_CH)];
        const _Float16 h = (_Float16)v;
        Wc[i] = __builtin_bit_cast(unsigned short, h);
    }
}

// ---------------------------------------------------------------------------
// K2 scan: exclusive prefix over 391 bins -> off[] (base) and gcursor[] (live)
// ---------------------------------------------------------------------------
__global__ __launch_bounds__(512) void scan_k(const int* __restrict__ ghist,
                                              int* __restrict__ off,
                                              int* __restrict__ gcursor) {
    __shared__ int sb[2][512];
    const int t = (int)threadIdx.x;
    const int v = (t < NPART) ? ghist[t] : 0;
    sb[0][t] = v;
    __syncthreads();
    int pb = 0;
    for (int o = 1; o < 512; o <<= 1) {
        sb[pb ^ 1][t] = sb[pb][t] + ((t >= o) ? sb[pb][t - o] : 0);
        pb ^= 1;
        __syncthreads();
    }
    const int excl = sb[pb][t] - v;
    off[t] = excl;
    gcursor[t] = excl;
}

// ---------------------------------------------------------------------------
// K3 part: counting-sort edges into partition buffers. Per-edge ops are LDS
// only; global atomics = one per (block,bin); writes are contiguous runs.
// ---------------------------------------------------------------------------
__global__ __launch_bounds__(256) void part_k(const int* __restrict__ ei,
                                              int* __restrict__ gcursor,
                                              int2* __restrict__ edgesP) {
    __shared__ int lhist[NPART + 1];
    __shared__ int lpre[NPART + 1];
    __shared__ int gbase[NPART + 1];
    __shared__ int2 stage[TILE];            // 32KB
    __shared__ unsigned short sbin[TILE];   // 8KB
    __shared__ int sb[2][512];

    const int tid = (int)threadIdx.x;
    const int e0 = (int)blockIdx.x * TILE;
    const int nv = min(TILE, N_EDGES - e0);

    for (int i = tid; i <= NPART; i += 256) lhist[i] = 0;
    __syncthreads();

    int esrc[16], emeta[16];
#pragma unroll
    for (int k = 0; k < 16; ++k) {
        const int e = e0 + k * 256 + tid;
        emeta[k] = -1;
        if (e < N_EDGES) {
            esrc[k] = ei[e];
            const int dst = ei[N_EDGES + e];
            const int bin = dst >> PSHIFT;
            const int dl = dst & (PSIZE - 1);
            const int rank = atomicAdd(&lhist[bin], 1);
            emeta[k] = bin | (dl << 9) | (rank << 17);
        }
    }
    __syncthreads();

    // 512-wide Hillis-Steele (2 elements/thread) -> block-local exclusive
    {
        const int i0 = tid, i1 = tid + 256;
        sb[0][i0] = (i0 < NPART) ? lhist[i0] : 0;
        sb[0][i1] = (i1 < NPART) ? lhist[i1] : 0;
        __syncthreads();
        int pb = 0;
        for (int o = 1; o < 512; o <<= 1) {
            sb[pb ^ 1][i0] = sb[pb][i0] + ((i0 >= o) ? sb[pb][i0 - o] : 0);
            sb[pb ^ 1][i1] = sb[pb][i1] + ((i1 >= o) ? sb[pb][i1 - o] : 0);
            pb ^= 1;
            __syncthreads();
        }
        if (i0 < NPART) lpre[i0] = sb[pb][i0] - lhist[i0];
        if (i1 < NPART) lpre[i1] = sb[pb][i1] - lhist[i1];
    }
    // reserve global space per bin
    for (int i = tid; i < NPART; i += 256)
        gbase[i] = lhist[i] ? atomicAdd(&gcursor[i], lhist[i]) : 0;
    __syncthreads();

#pragma unroll
    for (int k = 0; k < 16; ++k) {
        if (emeta[k] >= 0) {
            const int bin = emeta[k] & 511;
            const int dl = (emeta[k] >> 9) & 255;
            const int rank = emeta[k] >> 17;
            const int pos = lpre[bin] + rank;
            stage[pos] = make_int2(esrc[k], dl);
            sbin[pos] = (unsigned short)bin;
        }
    }
    __syncthreads();

    for (int i = tid; i < nv; i += 256) {
        const int b = sbin[i];
        edgesP[gbase[b] + (i - lpre[b])] = stage[i];
    }
}

// ---------------------------------------------------------------------------
// K4 meanp: one block per partition (256 nodes). Build per-dst CSR in LDS
// (hist+scan+reorder, all LDS ops), then 2 threads per dst gather neighbor
// rows with fully independent 16B loads, accumulate in registers.
// ---------------------------------------------------------------------------
__device__ __forceinline__ void acc8(float* a, uint4 v) {
    const half2v h0 = __builtin_bit_cast(half2v, v.x);
    const half2v h1 = __builtin_bit_cast(half2v, v.y);
    const half2v h2 = __builtin_bit_cast(half2v, v.z);
    const half2v h3 = __builtin_bit_cast(half2v, v.w);
    a[0] += (float)h0[0]; a[1] += (float)h0[1];
    a[2] += (float)h1[0]; a[3] += (float)h1[1];
    a[4] += (float)h2[0]; a[5] += (float)h2[1];
    a[6] += (float)h3[0]; a[7] += (float)h3[1];
}

__global__ __launch_bounds__(512) void meanp_k(const unsigned short* __restrict__ xh,
                                               const int* __restrict__ off,
                                               const int2* __restrict__ edgesP,
                                               unsigned short* __restrict__ meanh) {
    __shared__ unsigned short dl[MAXE];   // 8KB
    __shared__ unsigned short rk[MAXE];   // 8KB
    __shared__ int ss[MAXE];              // 16KB sorted srcs
    __shared__ int histL[PSIZE];
    __shared__ int rowp[PSIZE];
    __shared__ int sb[2][PSIZE];

    const int tid = (int)threadIdx.x;
    const int p = (int)blockIdx.x;
    const int node0 = p << PSHIFT;
    const int e0 = off[p];
    const int m = min(off[p + 1] - e0, MAXE);

    if (tid < PSIZE) histL[tid] = 0;
    __syncthreads();

    for (int i = tid; i < m; i += 512) {
        const int2 pr = edgesP[e0 + i];
        dl[i] = (unsigned short)pr.y;
        rk[i] = (unsigned short)atomicAdd(&histL[pr.y], 1);
    }
    __syncthreads();

    if (tid < PSIZE) sb[0][tid] = histL[tid];
    __syncthreads();
    int pb = 0;
    for (int o = 1; o < PSIZE; o <<= 1) {
        if (tid < PSIZE)
            sb[pb ^ 1][tid] = sb[pb][tid] + ((tid >= o) ? sb[pb][tid - o] : 0);
        pb ^= 1;
        __syncthreads();
    }
    if (tid < PSIZE) rowp[tid] = sb[pb][tid] - histL[tid];
    __syncthreads();

    for (int i = tid; i < m; i += 512)
        ss[rowp[dl[i]] + rk[i]] = edgesP[e0 + i].x;
    __syncthreads();

    const int owner = tid >> 1;
    const int half = tid & 1;
    const int node = node0 + owner;
    if (node >= N_NODES) return;

    const int deg = histL[owner];
    const int base = rowp[owner];

    float acc[32];
#pragma unroll
    for (int i = 0; i < 32; ++i) acc[i] = 0.f;

    int j = 0;
    for (; j + 2 <= deg; j += 2) {
        const int s0 = ss[base + j];
        const int s1 = ss[base + j + 1];
        const uint4* r0 = reinterpret_cast<const uint4*>(xh + (size_t)s0 * IN_CH + half * 32);
        const uint4* r1 = reinterpret_cast<const uint4*>(xh + (size_t)s1 * IN_CH + half * 32);
        uint4 a0 = r0[0], a1 = r0[1], a2 = r0[2], a3 = r0[3];
        uint4 b0 = r1[0], b1 = r1[1], b2 = r1[2], b3 = r1[3];
        acc8(acc + 0, a0); acc8(acc + 8, a1); acc8(acc + 16, a2); acc8(acc + 24, a3);
        acc8(acc + 0, b0); acc8(acc + 8, b1); acc8(acc + 16, b2); acc8(acc + 24, b3);
    }
    if (j < deg) {
        const int s0 = ss[base + j];
        const uint4* r0 = reinterpret_cast<const uint4*>(xh + (size_t)s0 * IN_CH + half * 32);
        uint4 a0 = r0[0], a1 = r0[1], a2 = r0[2], a3 = r0[3];
        acc8(acc + 0, a0); acc8(acc + 8, a1); acc8(acc + 16, a2); acc8(acc + 24, a3);
    }

    const float rcp = 1.0f / fmaxf((float)deg, 1.0f);
    uint4 ov[4];
#pragma unroll
    for (int c = 0; c < 4; ++c) {
        half2v l0, l1, l2, l3;
        l0[0] = (_Float16)(acc[c * 8 + 0] * rcp); l0[1] = (_Float16)(acc[c * 8 + 1] * rcp);
        l1[0] = (_Float16)(acc[c * 8 + 2] * rcp); l1[1] = (_Float16)(acc[c * 8 + 3] * rcp);
        l2[0] = (_Float16)(acc[c * 8 + 4] * rcp); l2[1] = (_Float16)(acc[c * 8 + 5] * rcp);
        l3[0] = (_Float16)(acc[c * 8 + 6] * rcp); l3[1] = (_Float16)(acc[c * 8 + 7] * rcp);
        ov[c].x = __builtin_bit_cast(unsigned, l0);
        ov[c].y = __builtin_bit_cast(unsigned, l1);
        ov[c].z = __builtin_bit_cast(unsigned, l2);
        ov[c].w = __builtin_bit_cast(unsigned, l3);
    }
    uint4* op = reinterpret_cast<uint4*>(meanh + (size_t)node * IN_CH + half * 32);
#pragma unroll
    for (int c = 0; c < 4; ++c) op[c] = ov[c];
}

// ---------------------------------------------------------------------------
// K5: MFMA GEMM (128-node x 128-out, K=128) + relu + per-graph max pool.
// (unchanged from R4 -- verified)
// ---------------------------------------------------------------------------
#define MBLK 128

__device__ __forceinline__ void flushmax(unsigned* lmax, unsigned int* gmax,
                                         int g, int gbase, int l15,
                                         const float* rmax) {
    const int slot = g - gbase;
    if (slot < 4) {
#pragma unroll
        for (int nt = 0; nt < 8; ++nt)
            atomicMax(&lmax[slot * HID + nt * 16 + l15], __float_as_uint(rmax[nt]));
    } else {
#pragma unroll
        for (int nt = 0; nt < 8; ++nt)
            atomicMax(&gmax[(size_t)g * HID + nt * 16 + l15], __float_as_uint(rmax[nt]));
    }
}

__global__ __launch_bounds__(512) void gemm_pool_k(const unsigned short* __restrict__ xh,
                                                   const unsigned short* __restrict__ meanh,
                                                   const unsigned short* __restrict__ Wc,
                                                   const float* __restrict__ b_l,
                                                   const int* __restrict__ batch,
                                                   unsigned int* __restrict__ gmax) {
    __shared__ uint4 fe[MBLK * 16];
    __shared__ uint4 wt[HID * 16];
    __shared__ unsigned lmax[4 * HID];
    __shared__ int bt[MBLK];

    const int tid = (int)threadIdx.x;
    const int nb = (int)blockIdx.x * MBLK;
    const int nvalid = min(MBLK, N_NODES - nb);

#pragma unroll
    for (int t = 0; t < 4; ++t) {
        const int id = tid + t * 512;
        const int row = id >> 4, c = id & 15;
        wt[row * 16 + (c ^ (row & 7))] = reinterpret_cast<const uint4*>(Wc)[row * 16 + c];
    }
#pragma unroll
    for (int t = 0; t < 4; ++t) {
        const int id = tid + t * 512;
        const int row = id >> 4, c = id & 15;
        const int n = nb + row;
        uint4 v = make_uint4(0u, 0u, 0u, 0u);
        if (n < N_NODES) {
            v = (c < 8) ? reinterpret_cast<const uint4*>(meanh)[(size_t)n * 8 + c]
                        : reinterpret_cast<const uint4*>(xh)[(size_t)n * 8 + (c - 8)];
        }
        fe[row * 16 + (c ^ (row & 7))] = v;
    }
    if (tid < MBLK) bt[tid] = (nb + tid < N_NODES) ? batch[nb + tid] : -1;
    for (int i = tid; i < 4 * HID; i += 512) lmax[i] = 0u;
    __syncthreads();

    const int lane = tid & 63;
    const int w = tid >> 6;
    const int l15 = lane & 15, q = lane >> 4;

    f32x4 acc[8];
#pragma unroll
    for (int nt = 0; nt < 8; ++nt) acc[nt] = (f32x4){0.f, 0.f, 0.f, 0.f};

    const int arow = w * 16 + l15;
#pragma unroll
    for (int kb = 0; kb < 4; ++kb) {
        const int ac = kb * 4 + q;
        const half8 a = __builtin_bit_cast(half8, fe[arow * 16 + (ac ^ (arow & 7))]);
#pragma unroll
        for (int nt = 0; nt < 8; ++nt) {
            const int nrow = nt * 16 + l15;
            const half8 b = __builtin_bit_cast(half8, wt[nrow * 16 + (ac ^ (nrow & 7))]);
            acc[nt] = __builtin_amdgcn_mfma_f32_16x16x32_f16(a, b, acc[nt], 0, 0, 0);
        }
    }

    float bias[8];
#pragma unroll
    for (int nt = 0; nt < 8; ++nt) bias[nt] = b_l[nt * 16 + l15];

    const int gbase = bt[0];
    const int rowb = w * 16 + q * 4;
    int curg = -1;
    float rmax[8];
#pragma unroll
    for (int nt = 0; nt < 8; ++nt) rmax[nt] = 0.f;

#pragma unroll
    for (int reg = 0; reg < 4; ++reg) {
        const int g = bt[rowb + reg];
        if (g >= 0) {
            float h[8];
#pragma unroll
            for (int nt = 0; nt < 8; ++nt) h[nt] = fmaxf(acc[nt][reg] + bias[nt], 0.f);
            if (g != curg) {
                if (curg >= 0) flushmax(lmax, gmax, curg, gbase, l15, rmax);
                curg = g;
#pragma unroll
                for (int nt = 0; nt < 8; ++nt) rmax[nt] = h[nt];
            } else {
#pragma unroll
                for (int nt = 0; nt < 8; ++nt) rmax[nt] = fmaxf(rmax[nt], h[nt]);
            }
        }
    }
    if (curg >= 0) flushmax(lmax, gmax, curg, gbase, l15, rmax);
    __syncthreads();

    int span = bt[nvalid - 1] - gbase + 1;
    if (span > 4) span = 4;
    for (int i = tid; i < span * HID; i += 512) {
        const unsigned v = lmax[i];
        if (v) atomicMax(&gmax[(size_t)(gbase + (i >> 7)) * HID + (i & 127)], v);
    }
}

// ---------------------------------------------------------------------------
// K6: head. out[g][oc] = gmax[g].W_lin[oc] + b_lin[oc]
// ---------------------------------------------------------------------------
__global__ __launch_bounds__(256) void head_k(const unsigned int* __restrict__ gmax_u,
                                              const float* __restrict__ W_lin,
                                              const float* __restrict__ b_lin,
                                              float* __restrict__ out) {
    const int t = (int)threadIdx.x;
    const int g = t >> 1;
    const int oc = t & 1;
    const float* gm = (const float*)gmax_u;
    float acc = b_lin[oc];
#pragma unroll 4
    for (int k = 0; k < HID; ++k) acc += gm[(size_t)g * HID + k] * W_lin[oc * HID + k];
    out[(size_t)g * OUT_CH + oc] = acc;
}

extern "C" void kernel_launch(void* const* d_in, const int* in_sizes, int n_in,
                              void* d_out, int out_size, void* d_ws, size_t ws_size,
                              hipStream_t stream) {
    const float* x = (const float*)d_in[0];
    const float* W_l = (const float*)d_in[1];
    const float* b_l = (const float*)d_in[2];
    const float* W_r = (const float*)d_in[3];
    const float* W_lin = (const float*)d_in[4];
    const float* b_lin = (const float*)d_in[5];
    const int* ei = (const int*)d_in[6];
    const int* batch = (const int*)d_in[7];
    float* out = (float*)d_out;

    char* ws = (char*)d_ws;
    size_t o = 0;
    int* ghist = (int*)(ws + o); o += 512 * 4;
    unsigned int* gmax = (unsigned int*)(ws + o); o += (size_t)NUM_GRAPHS * HID * 4;  // 64KB
    int* off = (int*)(ws + o); o += 512 * 4;
    int* gcursor = (int*)(ws + o); o += 512 * 4;
    int2* edgesP = (int2*)(ws + o); o += (size_t)N_EDGES * 8;                         // 10MB
    unsigned short* xh = (unsigned short*)(ws + o); o += (size_t)N_NODES * IN_CH * 2; // 12.8MB
    unsigned short* meanh = (unsigned short*)(ws + o); o += (size_t)N_NODES * IN_CH * 2;
    unsigned short* Wc = (unsigned short*)(ws + o); o += (size_t)HID * 2 * IN_CH * 2;

    // one memset covers ghist + gmax (adjacent)
    hipMemsetAsync(ghist, 0, 512 * 4 + (size_t)NUM_GRAPHS * HID * 4, stream);

    prep_k<<<HB + XCAST_BLOCKS + WPREP_BLOCKS, 256, 0, stream>>>(x, W_l, W_r, ei, xh, Wc, ghist);
    scan_k<<<1, 512, 0, stream>>>(ghist, off, gcursor);
    part_k<<<(N_EDGES + TILE - 1) / TILE, 256, 0, stream>>>(ei, gcursor, edgesP);
    meanp_k<<<NPART, 512, 0, stream>>>(xh, off, edgesP, meanh);
    gemm_pool_k<<<(N_NODES + MBLK - 1) / MBLK, 512, 0, stream>>>(xh, meanh, Wc, b_l, batch, gmax);
    head_k<<<1, 256, 0, stream>>>(gmax, W_lin, b_lin, out);
}

// Round 7
// 101.982 us; speedup vs baseline: 1.7706x; 1.0315x over previous
//
#include <hip/hip_runtime.h>

#define N_NODES 100000
#define N_EDGES 1250000
#define IN_CH 64
#define HID 128
#define OUT_CH 2
#define NUM_GRAPHS 128

#define PSHIFT 8
#define PSIZE 256                      // nodes per partition
#define NPART ((N_NODES + PSIZE - 1) / PSIZE)  // 391
#define MAXE 4096                      // max edges/partition (mean 3197, sigma 56 -> 16-sigma safe)
#define TILE 4096                      // edges per part_k block

typedef _Float16 half2v __attribute__((ext_vector_type(2)));
typedef _Float16 half8 __attribute__((ext_vector_type(8)));
typedef float f32x4 __attribute__((ext_vector_type(4)));

#define HB 64                                        // histogram blocks
#define XCAST_BLOCKS (N_NODES * IN_CH / 4 / 512)     // 3125 (2 float4 per thread)
#define WPREP_BLOCKS 64

// ---------------------------------------------------------------------------
// K1 prep: [0,HB) dst-histogram -> per-block slice (NO global atomics, no
// pre-zero needed), then x->f16 cast (2 float4/thread), then weight prep.
// ---------------------------------------------------------------------------
__global__ __launch_bounds__(256) void prep_k(const float* __restrict__ x,
                                              const float* __restrict__ W_l,
                                              const float* __restrict__ W_r,
                                              const int* __restrict__ ei,
                                              unsigned short* __restrict__ xh,
                                              unsigned short* __restrict__ Wc,
                                              int* __restrict__ ghist) {
    const int b = (int)blockIdx.x;
    const int tid = (int)threadIdx.x;
    if (b < HB) {
        __shared__ int lh[512];
        for (int i = tid; i < 512; i += 256) lh[i] = 0;
        __syncthreads();
        for (int e = b * 256 + tid; e < N_EDGES; e += HB * 256)
            atomicAdd(&lh[ei[N_EDGES + e] >> PSHIFT], 1);
        __syncthreads();
        // unconditional slice store: ghist needs no zeroing (ws may be poisoned)
        for (int i = tid; i < 512; i += 256) ghist[b * 512 + i] = lh[i];
        return;
    }
    const int b2 = b - HB;
    if (b2 < XCAST_BLOCKS) {
        const int i0 = b2 * 512 + tid;  // 2 float4 units per thread
#pragma unroll
        for (int t = 0; t < 2; ++t) {
            const int i = i0 + t * 256;
            const float4 v = reinterpret_cast<const float4*>(x)[i];
            half2v a, c;
            a[0] = (_Float16)v.x; a[1] = (_Float16)v.y;
            c[0] = (_Float16)v.z; c[1] = (_Float16)v.w;
            uint2 u;
            u.x = __builtin_bit_cast(unsigned, a);
            u.y = __builtin_bit_cast(unsigned, c);
            reinterpret_cast<uint2*>(xh)[i] = u;
        }
        return;
    }
    const int i = (b2 - XCAST_BLOCKS) * 256 + tid;
    if (i < HID * 2 * IN_CH) {
        const int o = i >> 7;
        const int k = i & 127;
        const float v = (k < IN_CH) ? W_l[o * IN_CH + k] : W_r[o * IN_CH + (k - IN_CH)];
        const _Float16 h = (_Float16)v;
        Wc[i] = __builtin_bit_cast(unsigned short, h);
    }
}

// ---------------------------------------------------------------------------
// K2 scan: reduce 64 hist slices, exclusive prefix -> off[] + gcursor[];
// also zeroes gmax (replaces the 42us fillBuffer dispatch).
// ---------------------------------------------------------------------------
__global__ __launch_bounds__(512) void scan_k(const int* __restrict__ ghist,
                                              int* __restrict__ off,
                                              int* __restrict__ gcursor,
                                              unsigned int* __restrict__ gmax) {
    __shared__ int sb[2][512];
    const int t = (int)threadIdx.x;
    int v = 0;
#pragma unroll 8
    for (int b = 0; b < HB; ++b) v += ghist[b * 512 + t];
    if (t >= NPART) v = 0;
    sb[0][t] = v;
    __syncthreads();
    int pb = 0;
    for (int o = 1; o < 512; o <<= 1) {
        sb[pb ^ 1][t] = sb[pb][t] + ((t >= o) ? sb[pb][t - o] : 0);
        pb ^= 1;
        __syncthreads();
    }
    const int excl = sb[pb][t] - v;
    off[t] = excl;
    gcursor[t] = excl;
#pragma unroll
    for (int i = 0; i < (NUM_GRAPHS * HID) / 512; ++i) gmax[i * 512 + t] = 0u;
}

// ---------------------------------------------------------------------------
// K3 part: counting-sort edges into partition buffers. Per-edge ops are LDS
// only; global atomics = one per (block,bin); writes are contiguous runs.
// ---------------------------------------------------------------------------
__global__ __launch_bounds__(256) void part_k(const int* __restrict__ ei,
                                              int* __restrict__ gcursor,
                                              int2* __restrict__ edgesP) {
    __shared__ int lhist[NPART + 1];
    __shared__ int lpre[NPART + 1];
    __shared__ int gbase[NPART + 1];
    __shared__ int2 stage[TILE];            // 32KB
    __shared__ unsigned short sbin[TILE];   // 8KB
    __shared__ int sb[2][512];

    const int tid = (int)threadIdx.x;
    const int e0 = (int)blockIdx.x * TILE;
    const int nv = min(TILE, N_EDGES - e0);

    for (int i = tid; i <= NPART; i += 256) lhist[i] = 0;
    __syncthreads();

    int esrc[16], emeta[16];
#pragma unroll
    for (int k = 0; k < 16; ++k) {
        const int e = e0 + k * 256 + tid;
        emeta[k] = -1;
        if (e < N_EDGES) {
            esrc[k] = ei[e];
            const int dst = ei[N_EDGES + e];
            const int bin = dst >> PSHIFT;
            const int dl = dst & (PSIZE - 1);
            const int rank = atomicAdd(&lhist[bin], 1);
            emeta[k] = bin | (dl << 9) | (rank << 17);
        }
    }
    __syncthreads();

    {
        const int i0 = tid, i1 = tid + 256;
        sb[0][i0] = (i0 < NPART) ? lhist[i0] : 0;
        sb[0][i1] = (i1 < NPART) ? lhist[i1] : 0;
        __syncthreads();
        int pb = 0;
        for (int o = 1; o < 512; o <<= 1) {
            sb[pb ^ 1][i0] = sb[pb][i0] + ((i0 >= o) ? sb[pb][i0 - o] : 0);
            sb[pb ^ 1][i1] = sb[pb][i1] + ((i1 >= o) ? sb[pb][i1 - o] : 0);
            pb ^= 1;
            __syncthreads();
        }
        if (i0 < NPART) lpre[i0] = sb[pb][i0] - lhist[i0];
        if (i1 < NPART) lpre[i1] = sb[pb][i1] - lhist[i1];
    }
    for (int i = tid; i < NPART; i += 256)
        gbase[i] = lhist[i] ? atomicAdd(&gcursor[i], lhist[i]) : 0;
    __syncthreads();

#pragma unroll
    for (int k = 0; k < 16; ++k) {
        if (emeta[k] >= 0) {
            const int bin = emeta[k] & 511;
            const int dl = (emeta[k] >> 9) & 255;
            const int rank = emeta[k] >> 17;
            const int pos = lpre[bin] + rank;
            stage[pos] = make_int2(esrc[k], dl);
            sbin[pos] = (unsigned short)bin;
        }
    }
    __syncthreads();

    for (int i = tid; i < nv; i += 256) {
        const int b = sbin[i];
        edgesP[gbase[b] + (i - lpre[b])] = stage[i];
    }
}

// ---------------------------------------------------------------------------
// K4 meanp: one block per partition (256 nodes). Build per-dst CSR in LDS,
// then 2 threads per dst gather neighbor rows (independent 16B loads).
// ---------------------------------------------------------------------------
__device__ __forceinline__ void acc8(float* a, uint4 v) {
    const half2v h0 = __builtin_bit_cast(half2v, v.x);
    const half2v h1 = __builtin_bit_cast(half2v, v.y);
    const half2v h2 = __builtin_bit_cast(half2v, v.z);
    const half2v h3 = __builtin_bit_cast(half2v, v.w);
    a[0] += (float)h0[0]; a[1] += (float)h0[1];
    a[2] += (float)h1[0]; a[3] += (float)h1[1];
    a[4] += (float)h2[0]; a[5] += (float)h2[1];
    a[6] += (float)h3[0]; a[7] += (float)h3[1];
}

__global__ __launch_bounds__(512) void meanp_k(const unsigned short* __restrict__ xh,
                                               const int* __restrict__ off,
                                               const int2* __restrict__ edgesP,
                                               unsigned short* __restrict__ meanh) {
    __shared__ unsigned short dl[MAXE];
    __shared__ unsigned short rk[MAXE];
    __shared__ int ss[MAXE];
    __shared__ int histL[PSIZE];
    __shared__ int rowp[PSIZE];
    __shared__ int sb[2][PSIZE];

    const int tid = (int)threadIdx.x;
    const int p = (int)blockIdx.x;
    const int node0 = p << PSHIFT;
    const int e0 = off[p];
    const int m = min(off[p + 1] - e0, MAXE);

    if (tid < PSIZE) histL[tid] = 0;
    __syncthreads();

    for (int i = tid; i < m; i += 512) {
        const int2 pr = edgesP[e0 + i];
        dl[i] = (unsigned short)pr.y;
        rk[i] = (unsigned short)atomicAdd(&histL[pr.y], 1);
    }
    __syncthreads();

    if (tid < PSIZE) sb[0][tid] = histL[tid];
    __syncthreads();
    int pb = 0;
    for (int o = 1; o < PSIZE; o <<= 1) {
        if (tid < PSIZE)
            sb[pb ^ 1][tid] = sb[pb][tid] + ((tid >= o) ? sb[pb][tid - o] : 0);
        pb ^= 1;
        __syncthreads();
    }
    if (tid < PSIZE) rowp[tid] = sb[pb][tid] - histL[tid];
    __syncthreads();

    for (int i = tid; i < m; i += 512)
        ss[rowp[dl[i]] + rk[i]] = edgesP[e0 + i].x;
    __syncthreads();

    const int owner = tid >> 1;
    const int half = tid & 1;
    const int node = node0 + owner;
    if (node >= N_NODES) return;

    const int deg = histL[owner];
    const int base = rowp[owner];

    float acc[32];
#pragma unroll
    for (int i = 0; i < 32; ++i) acc[i] = 0.f;

    int j = 0;
    for (; j + 2 <= deg; j += 2) {
        const int s0 = ss[base + j];
        const int s1 = ss[base + j + 1];
        const uint4* r0 = reinterpret_cast<const uint4*>(xh + (size_t)s0 * IN_CH + half * 32);
        const uint4* r1 = reinterpret_cast<const uint4*>(xh + (size_t)s1 * IN_CH + half * 32);
        uint4 a0 = r0[0], a1 = r0[1], a2 = r0[2], a3 = r0[3];
        uint4 b0 = r1[0], b1 = r1[1], b2 = r1[2], b3 = r1[3];
        acc8(acc + 0, a0); acc8(acc + 8, a1); acc8(acc + 16, a2); acc8(acc + 24, a3);
        acc8(acc + 0, b0); acc8(acc + 8, b1); acc8(acc + 16, b2); acc8(acc + 24, b3);
    }
    if (j < deg) {
        const int s0 = ss[base + j];
        const uint4* r0 = reinterpret_cast<const uint4*>(xh + (size_t)s0 * IN_CH + half * 32);
        uint4 a0 = r0[0], a1 = r0[1], a2 = r0[2], a3 = r0[3];
        acc8(acc + 0, a0); acc8(acc + 8, a1); acc8(acc + 16, a2); acc8(acc + 24, a3);
    }

    const float rcp = 1.0f / fmaxf((float)deg, 1.0f);
    uint4 ov[4];
#pragma unroll
    for (int c = 0; c < 4; ++c) {
        half2v l0, l1, l2, l3;
        l0[0] = (_Float16)(acc[c * 8 + 0] * rcp); l0[1] = (_Float16)(acc[c * 8 + 1] * rcp);
        l1[0] = (_Float16)(acc[c * 8 + 2] * rcp); l1[1] = (_Float16)(acc[c * 8 + 3] * rcp);
        l2[0] = (_Float16)(acc[c * 8 + 4] * rcp); l2[1] = (_Float16)(acc[c * 8 + 5] * rcp);
        l3[0] = (_Float16)(acc[c * 8 + 6] * rcp); l3[1] = (_Float16)(acc[c * 8 + 7] * rcp);
        ov[c].x = __builtin_bit_cast(unsigned, l0);
        ov[c].y = __builtin_bit_cast(unsigned, l1);
        ov[c].z = __builtin_bit_cast(unsigned, l2);
        ov[c].w = __builtin_bit_cast(unsigned, l3);
    }
    uint4* op = reinterpret_cast<uint4*>(meanh + (size_t)node * IN_CH + half * 32);
#pragma unroll
    for (int c = 0; c < 4; ++c) op[c] = ov[c];
}

// ---------------------------------------------------------------------------
// K5: MFMA GEMM (128-node x 128-out, K=128) + relu + per-graph max pool.
// ---------------------------------------------------------------------------
#define MBLK 128

__device__ __forceinline__ void flushmax(unsigned* lmax, unsigned int* gmax,
                                         int g, int gbase, int l15,
                                         const float* rmax) {
    const int slot = g - gbase;
    if (slot < 4) {
#pragma unroll
        for (int nt = 0; nt < 8; ++nt)
            atomicMax(&lmax[slot * HID + nt * 16 + l15], __float_as_uint(rmax[nt]));
    } else {
#pragma unroll
        for (int nt = 0; nt < 8; ++nt)
            atomicMax(&gmax[(size_t)g * HID + nt * 16 + l15], __float_as_uint(rmax[nt]));
    }
}

__global__ __launch_bounds__(512) void gemm_pool_k(const unsigned short* __restrict__ xh,
                                                   const unsigned short* __restrict__ meanh,
                                                   const unsigned short* __restrict__ Wc,
                                                   const float* __restrict__ b_l,
                                                   const int* __restrict__ batch,
                                                   unsigned int* __restrict__ gmax) {
    __shared__ uint4 fe[MBLK * 16];
    __shared__ uint4 wt[HID * 16];
    __shared__ unsigned lmax[4 * HID];
    __shared__ int bt[MBLK];

    const int tid = (int)threadIdx.x;
    const int nb = (int)blockIdx.x * MBLK;
    const int nvalid = min(MBLK, N_NODES - nb);

#pragma unroll
    for (int t = 0; t < 4; ++t) {
        const int id = tid + t * 512;
        const int row = id >> 4, c = id & 15;
        wt[row * 16 + (c ^ (row & 7))] = reinterpret_cast<const uint4*>(Wc)[row * 16 + c];
    }
#pragma unroll
    for (int t = 0; t < 4; ++t) {
        const int id = tid + t * 512;
        const int row = id >> 4, c = id & 15;
        const int n = nb + row;
        uint4 v = make_uint4(0u, 0u, 0u, 0u);
        if (n < N_NODES) {
            v = (c < 8) ? reinterpret_cast<const uint4*>(meanh)[(size_t)n * 8 + c]
                        : reinterpret_cast<const uint4*>(xh)[(size_t)n * 8 + (c - 8)];
        }
        fe[row * 16 + (c ^ (row & 7))] = v;
    }
    if (tid < MBLK) bt[tid] = (nb + tid < N_NODES) ? batch[nb + tid] : -1;
    for (int i = tid; i < 4 * HID; i += 512) lmax[i] = 0u;
    __syncthreads();

    const int lane = tid & 63;
    const int w = tid >> 6;
    const int l15 = lane & 15, q = lane >> 4;

    f32x4 acc[8];
#pragma unroll
    for (int nt = 0; nt < 8; ++nt) acc[nt] = (f32x4){0.f, 0.f, 0.f, 0.f};

    const int arow = w * 16 + l15;
#pragma unroll
    for (int kb = 0; kb < 4; ++kb) {
        const int ac = kb * 4 + q;
        const half8 a = __builtin_bit_cast(half8, fe[arow * 16 + (ac ^ (arow & 7))]);
#pragma unroll
        for (int nt = 0; nt < 8; ++nt) {
            const int nrow = nt * 16 + l15;
            const half8 b = __builtin_bit_cast(half8, wt[nrow * 16 + (ac ^ (nrow & 7))]);
            acc[nt] = __builtin_amdgcn_mfma_f32_16x16x32_f16(a, b, acc[nt], 0, 0, 0);
        }
    }

    float bias[8];
#pragma unroll
    for (int nt = 0; nt < 8; ++nt) bias[nt] = b_l[nt * 16 + l15];

    const int gbase = bt[0];
    const int rowb = w * 16 + q * 4;
    int curg = -1;
    float rmax[8];
#pragma unroll
    for (int nt = 0; nt < 8; ++nt) rmax[nt] = 0.f;

#pragma unroll
    for (int reg = 0; reg < 4; ++reg) {
        const int g = bt[rowb + reg];
        if (g >= 0) {
            float h[8];
#pragma unroll
            for (int nt = 0; nt < 8; ++nt) h[nt] = fmaxf(acc[nt][reg] + bias[nt], 0.f);
            if (g != curg) {
                if (curg >= 0) flushmax(lmax, gmax, curg, gbase, l15, rmax);
                curg = g;
#pragma unroll
                for (int nt = 0; nt < 8; ++nt) rmax[nt] = h[nt];
            } else {
#pragma unroll
                for (int nt = 0; nt < 8; ++nt) rmax[nt] = fmaxf(rmax[nt], h[nt]);
            }
        }
    }
    if (curg >= 0) flushmax(lmax, gmax, curg, gbase, l15, rmax);
    __syncthreads();

    int span = bt[nvalid - 1] - gbase + 1;
    if (span > 4) span = 4;
    for (int i = tid; i < span * HID; i += 512) {
        const unsigned v = lmax[i];
        if (v) atomicMax(&gmax[(size_t)(gbase + (i >> 7)) * HID + (i & 127)], v);
    }
}

// ---------------------------------------------------------------------------
// K6: head. out[g][oc] = gmax[g].W_lin[oc] + b_lin[oc]
// ---------------------------------------------------------------------------
__global__ __launch_bounds__(256) void head_k(const unsigned int* __restrict__ gmax_u,
                                              const float* __restrict__ W_lin,
                                              const float* __restrict__ b_lin,
                                              float* __restrict__ out) {
    const int t = (int)threadIdx.x;
    const int g = t >> 1;
    const int oc = t & 1;
    const float* gm = (const float*)gmax_u;
    float acc = b_lin[oc];
#pragma unroll 4
    for (int k = 0; k < HID; ++k) acc += gm[(size_t)g * HID + k] * W_lin[oc * HID + k];
    out[(size_t)g * OUT_CH + oc] = acc;
}

extern "C" void kernel_launch(void* const* d_in, const int* in_sizes, int n_in,
                              void* d_out, int out_size, void* d_ws, size_t ws_size,
                              hipStream_t stream) {
    const float* x = (const float*)d_in[0];
    const float* W_l = (const float*)d_in[1];
    const float* b_l = (const float*)d_in[2];
    const float* W_r = (const float*)d_in[3];
    const float* W_lin = (const float*)d_in[4];
    const float* b_lin = (const float*)d_in[5];
    const int* ei = (const int*)d_in[6];
    const int* batch = (const int*)d_in[7];
    float* out = (float*)d_out;

    char* ws = (char*)d_ws;
    size_t o = 0;
    int* ghist = (int*)(ws + o); o += (size_t)HB * 512 * 4;                            // 128KB slices
    unsigned int* gmax = (unsigned int*)(ws + o); o += (size_t)NUM_GRAPHS * HID * 4;   // 64KB
    int* off = (int*)(ws + o); o += 512 * 4;
    int* gcursor = (int*)(ws + o); o += 512 * 4;
    int2* edgesP = (int2*)(ws + o); o += (size_t)N_EDGES * 8;                          // 10MB
    unsigned short* xh = (unsigned short*)(ws + o); o += (size_t)N_NODES * IN_CH * 2;  // 12.8MB
    unsigned short* meanh = (unsigned short*)(ws + o); o += (size_t)N_NODES * IN_CH * 2;
    unsigned short* Wc = (unsigned short*)(ws + o); o += (size_t)HID * 2 * IN_CH * 2;

    // no memsets: ghist is slice-overwritten, gmax zeroed in scan_k,
    // off/gcursor written in scan_k, edgesP fully overwritten by part_k.

    prep_k<<<HB + XCAST_BLOCKS + WPREP_BLOCKS, 256, 0, stream>>>(x, W_l, W_r, ei, xh, Wc, ghist);
    scan_k<<<1, 512, 0, stream>>>(ghist, off, gcursor, gmax);
    part_k<<<(N_EDGES + TILE - 1) / TILE, 256, 0, stream>>>(ei, gcursor, edgesP);
    meanp_k<<<NPART, 512, 0, stream>>>(xh, off, edgesP, meanh);
    gemm_pool_k<<<(N_NODES + MBLK - 1) / MBLK, 512, 0, stream>>>(xh, meanh, Wc, b_l, batch, gmax);
    head_k<<<1, 256, 0, stream>>>(gmax, W_lin, b_lin, out);
}